// Round 6
// baseline (111.347 us; speedup 1.0000x reference)
//
#include <hip/hip_runtime.h>
#include <math.h>

typedef unsigned short u16;
typedef unsigned int u32;
typedef __bf16 bf16x8 __attribute__((ext_vector_type(8)));
typedef float f32x4 __attribute__((ext_vector_type(4)));

__device__ __forceinline__ u16 f2b(float f) {
  u32 u = __builtin_bit_cast(u32, f);
  u32 r = (u + 0x7FFFu + ((u >> 16) & 1u)) >> 16;
  return (u16)r;
}

__device__ __forceinline__ void glds16(const void* g, void* lds) {
  __builtin_amdgcn_global_load_lds(
      (const __attribute__((address_space(1))) void*)(void*)(const_cast<void*>(g)),
      (__attribute__((address_space(3))) void*)lds, 16, 0, 0);
}

// ---------------- prep kernels ----------------

__global__ __launch_bounds__(256) void castx(const float* __restrict__ x, u16* __restrict__ xb) {
  int idx = blockIdx.x * 256 + threadIdx.x;
  float4 v = ((const float4*)x)[idx];
  ushort4 o;
  o.x = f2b(v.x); o.y = f2b(v.y); o.z = f2b(v.z); o.w = f2b(v.w);
  ((ushort4*)xb)[idx] = o;
}

__global__ __launch_bounds__(256) void buildw(const float* __restrict__ Wq, const float* __restrict__ Wk,
                                              const float* __restrict__ Wv, const float* __restrict__ Wo,
                                              u16* __restrict__ WbigT, u16* __restrict__ WoT) {
  const float SCALE = 0.08838834764831845f;  // 1/sqrt(128)
  int row = blockIdx.x;  // 0..2055
  int t = threadIdx.x;
  if (row < 512) {
    for (int k = t; k < 512; k += 256) WbigT[row*512 + k] = f2b(Wq[k*512 + row] * SCALE);
  } else if (row < 1024) {
    int n = row - 512;
    for (int k = t; k < 512; k += 256) WbigT[row*512 + k] = f2b(Wk[k*512 + n]);
  } else if (row < 1536) {
    int n = row - 1024;
    for (int k = t; k < 512; k += 256) WbigT[row*512 + k] = f2b(Wv[k*512 + n]);
  } else if (row < 1544) {
    int rr = row - 1536 + 2040;
    for (int k = t; k < 512; k += 256) WbigT[rr*512 + k] = 0;
  } else {
    int n = row - 1544;
    for (int k = t; k < 512; k += 256) WoT[n*512 + k] = f2b(Wo[k*512 + n]);
  }
}

__global__ __launch_bounds__(256) void wpe_kernel(const float* __restrict__ Wq, const float* __restrict__ pew,
                                                  const float* __restrict__ peh, u16* __restrict__ WbigT) {
  int k = blockIdx.x;  // 0..511
  int t = threadIdx.x;
  __shared__ float wrow[512];
  for (int j = t; j < 512; j += 256) wrow[j] = Wq[k*512 + j];
  __syncthreads();
  if (t < 252) {
    int h = t / 63, r = t - h*63;
    float aw = 0.f, ah = 0.f;
    for (int d = 0; d < 128; d++) {
      float qv = wrow[h*128 + d];
      aw += qv * pew[d*63 + r];
      ah += qv * peh[d*63 + r];
    }
    const float SCALE = 0.08838834764831845f;
    WbigT[(size_t)(1536 + t)*512 + k] = f2b(aw * SCALE);
    WbigT[(size_t)(1788 + t)*512 + k] = f2b(ah * SCALE);
  }
}

// ---------------- QKV+REL GEMM, barrier-free K-loop ----------------
// Block = 512 M-rows x 128 N-cols, 8 waves (each 64 rows x 128 cols).
// B-panel (128 n-rows x 512 k) staged ONCE in LDS (swizzled); A-fragments loaded
// directly from global (L2-hot) per MFMA. No barriers / no staging in the K-loop.
__global__ __launch_bounds__(512, 2) void gemm_qkv(
    const u16* __restrict__ A, const u16* __restrict__ Bt,
    u16* __restrict__ Qb, u16* __restrict__ Kb, u16* __restrict__ Vt,
    float* __restrict__ RELW, float* __restrict__ RELH)
{
  __shared__ char sm[131072];   // B-panel [128][1024B] swizzled; reused by epilogue
  const int tid = threadIdx.x;
  const int w = tid >> 6, l = tid & 63, g = l >> 4, c = l & 15;
  const int bm = blockIdx.x, bn = blockIdx.y;   // 16 x 16

  // stage B-panel once (row n&7 == w -> wave-uniform swizzle key)
  {
    const char* Bb = (const char*)Bt;
#pragma unroll
    for (int u = 0; u < 16; u++) {
      const int n = u*8 + w;
      glds16(Bb + (size_t)(bn*128 + n)*1024 + ((l*16) ^ ((n & 7) << 4)),
             sm + u*8192 + w*1024);
    }
    asm volatile("s_waitcnt vmcnt(0)" ::: "memory");
    __builtin_amdgcn_s_barrier();
  }

  f32x4 acc[4][8];
#pragma unroll
  for (int i = 0; i < 4; i++)
#pragma unroll
    for (int j = 0; j < 8; j++) acc[i][j] = f32x4{0.f, 0.f, 0.f, 0.f};

  const char* Ab = (const char*)A + (size_t)(bm*512 + w*64 + c)*1024 + g*16;

#pragma unroll 4
  for (int kb = 0; kb < 16; kb++) {
    bf16x8 af[4];
#pragma unroll
    for (int mf = 0; mf < 4; mf++)
      af[mf] = *(const bf16x8*)(Ab + mf*16384 + kb*64);
    bf16x8 bfr[8];
#pragma unroll
    for (int nf = 0; nf < 8; nf++)
      bfr[nf] = *(const bf16x8*)(sm + (nf*16 + c)*1024 + ((kb*64 + g*16) ^ ((c & 7) << 4)));
#pragma unroll
    for (int mf = 0; mf < 4; mf++)
#pragma unroll
      for (int nf = 0; nf < 8; nf++)
        acc[mf][nf] = __builtin_amdgcn_mfma_f32_16x16x32_bf16(af[mf], bfr[nf], acc[mf][nf], 0, 0, 0);
  }

  __builtin_amdgcn_s_barrier();   // all waves done reading B-panel; sm is now scratch

  const int b = bm >> 1;
  const int iB = (bm & 1) * 512;

  if (bn < 8) {
    // Q (bn<4, h=bn) / K (h=bn-4): LDS [m_local 512][d 128] bf16 swizzled -> 16B stores
    u16* dst0 = (bn < 4) ? Qb : Kb;
    const int h = bn & 3;
#pragma unroll
    for (int mf = 0; mf < 4; mf++) {
#pragma unroll
      for (int nf = 0; nf < 8; nf++) {
        const int d = nf*16 + c;
#pragma unroll
        for (int r = 0; r < 4; r++) {
          const int ml = w*64 + mf*16 + g*4 + r;
          *(u16*)(sm + ml*256 + ((d*2) ^ ((ml & 7) << 4))) = f2b(acc[mf][nf][r]);
        }
      }
    }
    __builtin_amdgcn_s_barrier();
#pragma unroll
    for (int it = 0; it < 16; it++) {
      const int chunk = it*512 + tid;
      const int ml = chunk >> 4, d0 = (chunk & 15) * 8;
      bf16x8 v = *(const bf16x8*)(sm + ml*256 + ((d0*2) ^ ((ml & 7) << 4)));
      *(bf16x8*)(dst0 + ((size_t)(b*4 + h)*1024 + iB + ml)*128 + d0) = v;
    }
  } else if (bn < 12) {
    // V (h=bn-8): LDS [d 128][m_local 512] bf16 (cvt_pk 8B writes) -> coalesced V^T stores
    const int h = bn - 8;
#pragma unroll
    for (int mf = 0; mf < 4; mf++) {
      const int mlb = w*64 + mf*16 + g*4;
#pragma unroll
      for (int nf = 0; nf < 8; nf++) {
        const int d = nf*16 + c;
        u32 w0, w1;
        asm("v_cvt_pk_bf16_f32 %0, %1, %2" : "=v"(w0) : "v"(acc[mf][nf][0]), "v"(acc[mf][nf][1]));
        asm("v_cvt_pk_bf16_f32 %0, %1, %2" : "=v"(w1) : "v"(acc[mf][nf][2]), "v"(acc[mf][nf][3]));
        uint2 pk; pk.x = w0; pk.y = w1;
        *(uint2*)(sm + d*1024 + ((mlb*2) ^ ((d & 7) << 4))) = pk;
      }
    }
    __builtin_amdgcn_s_barrier();
#pragma unroll
    for (int it = 0; it < 16; it++) {
      const int chunk = it*512 + tid;
      const int d = chunk >> 6, m0 = (chunk & 63) * 8;
      bf16x8 v = *(const bf16x8*)(sm + d*1024 + ((m0*2) ^ ((d & 7) << 4)));
      *(bf16x8*)(Vt + ((size_t)(b*4 + h)*128 + d)*1024 + iB + m0) = v;
    }
  } else {
    // REL: q = (bn-12)*128 + nf*16 + c in [0,512); q<252 -> RELW, 252<=q<504 -> RELH
#pragma unroll
    for (int mf = 0; mf < 4; mf++) {
      const int mlb = w*64 + mf*16 + g*4;
#pragma unroll
      for (int nf = 0; nf < 8; nf++) {
        const int q = (bn - 12)*128 + nf*16 + c;
        if (q < 252) {
          const int h = q / 63, r2 = q - h*63;
#pragma unroll
          for (int r = 0; r < 4; r++)
            RELW[(size_t)((b*4 + h)*1024 + iB + mlb + r)*64 + r2] = acc[mf][nf][r];
        } else if (q < 504) {
          const int qq = q - 252;
          const int h = qq / 63, r2 = qq - h*63;
#pragma unroll
          for (int r = 0; r < 4; r++)
            RELH[(size_t)((b*4 + h)*1024 + iB + mlb + r)*64 + r2] = acc[mf][nf][r];
        }
      }
    }
  }
}

// ---------------- output GEMM, barrier-free K-loop (BN=64, 2 blocks/CU) ----------------
__global__ __launch_bounds__(256) void gemm_out(
    const u16* __restrict__ A, const u16* __restrict__ Bt, float* __restrict__ outF)
{
  __shared__ char sm[65536];    // B-panel [64][1024B] swizzled
  const int tid = threadIdx.x;
  const int w = tid >> 6, l = tid & 63, g = l >> 4, c = l & 15;
  const int bm = blockIdx.x, bn = blockIdx.y;   // 32 x 8

  {
    const char* Bb = (const char*)Bt;
#pragma unroll
    for (int u = 0; u < 16; u++) {
      const int n = u*4 + w;
      glds16(Bb + (size_t)(bn*64 + n)*1024 + ((l*16) ^ ((n & 7) << 4)),
             sm + u*4096 + w*1024);
    }
    asm volatile("s_waitcnt vmcnt(0)" ::: "memory");
    __builtin_amdgcn_s_barrier();
  }

  f32x4 acc[4][4];
#pragma unroll
  for (int i = 0; i < 4; i++)
#pragma unroll
    for (int j = 0; j < 4; j++) acc[i][j] = f32x4{0.f, 0.f, 0.f, 0.f};

  const char* Ab = (const char*)A + (size_t)(bm*256 + w*64 + c)*1024 + g*16;

#pragma unroll 4
  for (int kb = 0; kb < 16; kb++) {
    bf16x8 af[4];
#pragma unroll
    for (int mf = 0; mf < 4; mf++)
      af[mf] = *(const bf16x8*)(Ab + mf*16384 + kb*64);
    bf16x8 bfr[4];
#pragma unroll
    for (int nf = 0; nf < 4; nf++)
      bfr[nf] = *(const bf16x8*)(sm + (nf*16 + c)*1024 + ((kb*64 + g*16) ^ ((c & 7) << 4)));
#pragma unroll
    for (int mf = 0; mf < 4; mf++)
#pragma unroll
      for (int nf = 0; nf < 4; nf++)
        acc[mf][nf] = __builtin_amdgcn_mfma_f32_16x16x32_bf16(af[mf], bfr[nf], acc[mf][nf], 0, 0, 0);
  }

#pragma unroll
  for (int mf = 0; mf < 4; mf++) {
#pragma unroll
    for (int nf = 0; nf < 4; nf++) {
      const int n = bn*64 + nf*16 + c;
#pragma unroll
      for (int r = 0; r < 4; r++) {
        const int m = bm*256 + w*64 + mf*16 + g*4 + r;
        outF[(size_t)m*512 + n] = acc[mf][nf][r];
      }
    }
  }
}

// ---------------- fused flash attention, SWAPPED QK^T (unchanged from R4) ----------------
__global__ __launch_bounds__(256) void attn_fused(
    const u16* __restrict__ Qb, const u16* __restrict__ Kb, const u16* __restrict__ Vt,
    const float* __restrict__ RELW, const float* __restrict__ RELH,
    u16* __restrict__ AO)
{
  __shared__ char sm[73728];   // [p][Kt 16KB][Vts 16KB] x2, Pl 8KB
  char* const Pl = sm + 65536;
  const int tid = threadIdx.x;
  const int w = tid >> 6, l = tid & 63, g = l >> 4, c = l & 15;
  const int bh = blockIdx.x, qt = blockIdx.y;
  const int i0 = qt * 64;

  bf16x8 qf[4];
  {
    const char* qbase = (const char*)Qb + (size_t)(bh*1024 + i0 + w*16 + c) * 256;
#pragma unroll
    for (int s = 0; s < 4; s++) qf[s] = *(const bf16x8*)(qbase + s*64 + g*16);
  }

  const int i = i0 + w*16 + c;
  const int xi = i & 31, yi = i >> 5;
  const float* rw = RELW + ((size_t)(bh*1024 + i) << 6);
  const float* rhb = RELH + ((size_t)(bh*1024 + i) << 6) + (31 - yi);
  float xwh[2][4];
#pragma unroll
  for (int e = 0; e < 2; e++)
#pragma unroll
    for (int r = 0; r < 4; r++) xwh[e][r] = rw[e*16 + g*4 + r - xi + 31];

  f32x4 Oacc[8];
#pragma unroll
  for (int fd = 0; fd < 8; fd++) Oacc[fd] = f32x4{0.f, 0.f, 0.f, 0.f};
  float m_q = -INFINITY, l_q = 0.f;

#define A_STAGE(jt, p)                                                                     \
  {                                                                                        \
    char* Kt_ = sm + (p)*32768;                                                            \
    char* Vs_ = Kt_ + 16384;                                                               \
    const int j0b = (jt) * 64;                                                             \
    _Pragma("unroll")                                                                      \
    for (int t = 0; t < 4; t++) {                                                          \
      const int L = (w*4 + t)*1024 + l*16;                                                 \
      const int jr = L >> 8, jb = L & 255;                                                 \
      glds16((const char*)Kb + (size_t)(bh*1024 + j0b + jr) * 256 + (jb ^ ((jr & 7) << 4)),\
             Kt_ + L);                                                                     \
      const int dr = L >> 7, db = L & 127;                                                 \
      glds16((const char*)Vt + (size_t)(bh*128 + dr) * 2048 + j0b*2 + (db ^ ((dr & 7) << 4)),\
             Vs_ + L);                                                                     \
    }                                                                                      \
  }

  A_STAGE(0, 0);
  A_STAGE(1, 1);
  float yh0 = rhb[0], yh1 = rhb[1];

#pragma unroll 2
  for (int jt = 0; jt < 16; jt++) {
    const int p = jt & 1;
    if (jt < 15) { asm volatile("s_waitcnt vmcnt(8)" ::: "memory"); }
    else         { asm volatile("s_waitcnt vmcnt(0)" ::: "memory"); }
    __builtin_amdgcn_s_barrier();

    const char* Kt_ = sm + p*32768;
    const char* Vs_ = Kt_ + 16384;

    f32x4 acc[4];
#pragma unroll
    for (int fn = 0; fn < 4; fn++) acc[fn] = f32x4{0.f, 0.f, 0.f, 0.f};
    __builtin_amdgcn_s_setprio(1);
#pragma unroll
    for (int s = 0; s < 4; s++) {
      const int koff = (s*64 + g*16) ^ ((c & 7) << 4);
#pragma unroll
      for (int fn = 0; fn < 4; fn++) {
        bf16x8 kf = *(const bf16x8*)(Kt_ + (fn*16 + c)*256 + koff);
        acc[fn] = __builtin_amdgcn_mfma_f32_16x16x32_bf16(kf, qf[s], acc[fn], 0, 0, 0);
      }
    }
    __builtin_amdgcn_s_setprio(0);

#pragma unroll
    for (int fn = 0; fn < 4; fn++)
#pragma unroll
      for (int r = 0; r < 4; r++)
        acc[fn][r] += xwh[fn & 1][r] + ((fn >> 1) ? yh1 : yh0);

    float mx = fmaxf(fmaxf(fmaxf(acc[0][0], acc[0][1]), fmaxf(acc[0][2], acc[0][3])),
                     fmaxf(fmaxf(acc[1][0], acc[1][1]), fmaxf(acc[1][2], acc[1][3])));
    mx = fmaxf(mx, fmaxf(fmaxf(fmaxf(acc[2][0], acc[2][1]), fmaxf(acc[2][2], acc[2][3])),
                         fmaxf(fmaxf(acc[3][0], acc[3][1]), fmaxf(acc[3][2], acc[3][3]))));
    mx = fmaxf(mx, __shfl_xor(mx, 16));
    mx = fmaxf(mx, __shfl_xor(mx, 32));
    const float mnew = fmaxf(m_q, mx);
    const float scq = __expf(m_q - mnew);
    m_q = mnew;

    float pv[4][4];
    float ps = 0.f;
#pragma unroll
    for (int fn = 0; fn < 4; fn++) {
#pragma unroll
      for (int r = 0; r < 4; r++) {
        pv[fn][r] = __expf(acc[fn][r] - mnew);
        ps += pv[fn][r];
      }
    }
    ps += __shfl_xor(ps, 16);
    ps += __shfl_xor(ps, 32);
    l_q = l_q * scq + ps;

    float nyh0 = 0.f, nyh1 = 0.f;
    if (jt < 15) { nyh0 = rhb[(jt + 1)*2]; nyh1 = rhb[(jt + 1)*2 + 1]; }

    {
      char* pb = Pl + w*2048 + c*128;
      const int swz = (c & 7) << 4;
#pragma unroll
      for (int fn = 0; fn < 4; fn++) {
        u32 w0, w1;
        asm("v_cvt_pk_bf16_f32 %0, %1, %2" : "=v"(w0) : "v"(pv[fn][0]), "v"(pv[fn][1]));
        asm("v_cvt_pk_bf16_f32 %0, %1, %2" : "=v"(w1) : "v"(pv[fn][2]), "v"(pv[fn][3]));
        uint2 pk; pk.x = w0; pk.y = w1;
        *(uint2*)(pb + ((fn*32 + g*8) ^ swz)) = pk;
      }
    }

#pragma unroll
    for (int r = 0; r < 4; r++) {
      const float scr = __shfl(scq, g*4 + r, 16);
#pragma unroll
      for (int fd = 0; fd < 8; fd++) Oacc[fd][r] *= scr;
    }

    __builtin_amdgcn_s_setprio(1);
#pragma unroll
    for (int s = 0; s < 2; s++) {
      const int koff = (s*64 + g*16) ^ ((c & 7) << 4);
      bf16x8 pf = *(const bf16x8*)(Pl + w*2048 + c*128 + koff);
#pragma unroll
      for (int fd = 0; fd < 8; fd++) {
        bf16x8 vf = *(const bf16x8*)(Vs_ + (fd*16 + c)*128 + koff);
        Oacc[fd] = __builtin_amdgcn_mfma_f32_16x16x32_bf16(pf, vf, Oacc[fd], 0, 0, 0);
      }
    }
    __builtin_amdgcn_s_setprio(0);

    __builtin_amdgcn_s_barrier();
    if (jt < 14) A_STAGE(jt + 2, p);
    yh0 = nyh0; yh1 = nyh1;
  }

  const int b = bh >> 2, h = bh & 3;
#pragma unroll
  for (int r = 0; r < 4; r++) {
    const float lr = __shfl(l_q, g*4 + r, 16);
    const float linv = 1.0f / lr;
    const int io = i0 + w*16 + g*4 + r;
#pragma unroll
    for (int fd = 0; fd < 8; fd++) {
      AO[(size_t)(b*1024 + io)*512 + h*128 + fd*16 + c] = f2b(Oacc[fd][r] * linv);
    }
  }
#undef A_STAGE
}

// ---------------- launcher ----------------
extern "C" void kernel_launch(void* const* d_in, const int* in_sizes, int n_in,
                              void* d_out, int out_size, void* d_ws, size_t ws_size,
                              hipStream_t stream) {
  const float* x   = (const float*)d_in[0];
  const float* Wq  = (const float*)d_in[1];
  const float* Wk  = (const float*)d_in[2];
  const float* Wv  = (const float*)d_in[3];
  const float* Wo  = (const float*)d_in[4];
  const float* pew = (const float*)d_in[5];
  const float* peh = (const float*)d_in[6];

  char* ws = (char*)d_ws;
  u16* xb    = (u16*)ws;    ws += (size_t)8192*512*2;
  u16* WbigT = (u16*)ws;    ws += (size_t)2048*512*2;
  u16* WoT   = (u16*)ws;    ws += (size_t)512*512*2;
  u16* Qb    = (u16*)ws;    ws += (size_t)32*1024*128*2;
  u16* Kb    = (u16*)ws;    ws += (size_t)32*1024*128*2;
  u16* Vt    = (u16*)ws;    ws += (size_t)32*1024*128*2;
  float* RELW = (float*)ws; ws += (size_t)32*1024*64*4;
  float* RELH = (float*)ws; ws += (size_t)32*1024*64*4;
  u16* AO    = (u16*)ws;    ws += (size_t)8192*512*2;

  castx<<<4096, 256, 0, stream>>>(x, xb);
  buildw<<<2056, 256, 0, stream>>>(Wq, Wk, Wv, Wo, WbigT, WoT);
  wpe_kernel<<<512, 256, 0, stream>>>(Wq, pew, peh, WbigT);
  gemm_qkv<<<dim3(16, 16), 512, 0, stream>>>(xb, WbigT, Qb, Kb, Vt, RELW, RELH);
  attn_fused<<<dim3(32, 16), 256, 0, stream>>>(Qb, Kb, Vt, RELW, RELH, AO);
  gemm_out<<<dim3(32, 8), 256, 0, stream>>>(AO, WoT, (float*)d_out);
}